// Round 2
// 346.784 us; speedup vs baseline: 1.0305x; 1.0305x over previous
//
#include <hip/hip_runtime.h>
#include <math.h>

#define NEG_SLOPE 0.2f
#define BN_EPS 1e-5f

// ---------- helpers ----------

__device__ __forceinline__ void edge_sd(const int* __restrict__ ei, int E, int eid, int& s, int& d) {
    if (eid < E) { s = ei[eid]; d = ei[E + eid]; }
    else         { s = d = eid - E; }   // self-loops appended after the E real edges
}

__device__ __forceinline__ float lrelu(float v) { return v > 0.f ? v : NEG_SLOPE * v; }

// round-to-nearest-even fp32 -> bf16 bits
__device__ __forceinline__ unsigned short f2bf(float f) {
    unsigned u = __float_as_uint(f);
    u += 0x7fffu + ((u >> 16) & 1u);
    return (unsigned short)(u >> 16);
}

// ---------- GEMM: act(X)[N,128] @ W[128,128] -> bf16 shadow + fused attention logits ----------
// fp32 output is DEAD (att fused here, agg reads bf16) -> only Ybf + a_src/a_dst written.
// If bnmu != nullptr, applies BN+ELU to X elements while staging into LDS.
__global__ __launch_bounds__(256) void gemm128(const float* __restrict__ X,
                                               const float* __restrict__ W,
                                               unsigned short* __restrict__ Ybf,
                                               const float* __restrict__ att_s,
                                               const float* __restrict__ att_d,
                                               float* __restrict__ a_srcO,
                                               float* __restrict__ a_dstO,
                                               const float* __restrict__ bnmu,
                                               const float* __restrict__ bnrs,
                                               const float* __restrict__ gamma,
                                               const float* __restrict__ beta,
                                               int Nrows) {
    __shared__ float xs[64 * 128];
    int bm = blockIdx.x * 64;
    int tid = threadIdx.x;

    const float4* Xv = (const float4*)(X + (size_t)bm * 128);
    float4* xsv = (float4*)xs;
    if (bnmu == nullptr) {
        for (int i = tid; i < 64 * 32; i += 256) {
            int row = i >> 5;
            xsv[i] = (bm + row < Nrows) ? Xv[i] : make_float4(0.f, 0.f, 0.f, 0.f);
        }
    } else {
        for (int i = tid; i < 64 * 32; i += 256) {
            int row = i >> 5;
            int cb = (i & 31) * 4;
            float4 v = (bm + row < Nrows) ? Xv[i] : make_float4(0.f, 0.f, 0.f, 0.f);
            float4 m4 = *(const float4*)(bnmu + cb);
            float4 r4 = *(const float4*)(bnrs + cb);
            float4 g4 = *(const float4*)(gamma + cb);
            float4 b4 = *(const float4*)(beta + cb);
            v.x = (v.x - m4.x) * r4.x * g4.x + b4.x;
            v.y = (v.y - m4.y) * r4.y * g4.y + b4.y;
            v.z = (v.z - m4.z) * r4.z * g4.z + b4.z;
            v.w = (v.w - m4.w) * r4.w * g4.w + b4.w;
            v.x = v.x > 0.f ? v.x : expm1f(v.x);
            v.y = v.y > 0.f ? v.y : expm1f(v.y);
            v.z = v.z > 0.f ? v.z : expm1f(v.z);
            v.w = v.w > 0.f ? v.w : expm1f(v.w);
            xsv[i] = v;
        }
    }
    __syncthreads();

    int cq = tid & 31;     // column quad: cols cq*4..cq*4+3
    int rg = tid >> 5;     // row group: rows rg*8..rg*8+7
    int lane = tid & 63;

    float acc[8][4];
#pragma unroll
    for (int r = 0; r < 8; r++)
#pragma unroll
        for (int j = 0; j < 4; j++) acc[r][j] = 0.f;

    const float* xbase = xs + (rg * 8) * 128;
#pragma unroll 2
    for (int k4 = 0; k4 < 32; k4++) {
        const float* wrow = W + k4 * 4 * 128 + cq * 4;
        float4 w0 = *(const float4*)(wrow);
        float4 w1 = *(const float4*)(wrow + 128);
        float4 w2 = *(const float4*)(wrow + 256);
        float4 w3 = *(const float4*)(wrow + 384);
#pragma unroll
        for (int r = 0; r < 8; r++) {
            float4 x4 = *(const float4*)(xbase + r * 128 + k4 * 4);   // ds_read_b128
            acc[r][0] += x4.x * w0.x; acc[r][1] += x4.x * w0.y;
            acc[r][2] += x4.x * w0.z; acc[r][3] += x4.x * w0.w;
            acc[r][0] += x4.y * w1.x; acc[r][1] += x4.y * w1.y;
            acc[r][2] += x4.y * w1.z; acc[r][3] += x4.y * w1.w;
            acc[r][0] += x4.z * w2.x; acc[r][1] += x4.z * w2.y;
            acc[r][2] += x4.z * w2.z; acc[r][3] += x4.z * w2.w;
            acc[r][0] += x4.w * w3.x; acc[r][1] += x4.w * w3.y;
            acc[r][2] += x4.w * w3.z; acc[r][3] += x4.w * w3.w;
        }
    }

    // fused attention-logit epilogue: this thread owns head h = cq>>2, cols (cq&3)*4..+3 of it
    int h = cq >> 2;
    float4 as4 = *(const float4*)(att_s + h * 16 + (cq & 3) * 4);
    float4 ad4 = *(const float4*)(att_d + h * 16 + (cq & 3) * 4);

#pragma unroll
    for (int r = 0; r < 8; r++) {
        int row = bm + rg * 8 + r;
        float ps = acc[r][0] * as4.x + acc[r][1] * as4.y + acc[r][2] * as4.z + acc[r][3] * as4.w;
        float pd = acc[r][0] * ad4.x + acc[r][1] * ad4.y + acc[r][2] * ad4.z + acc[r][3] * ad4.w;
        // reduce across the 4 lanes of this head (same row, adjacent cq)
        ps += __shfl_xor(ps, 1); ps += __shfl_xor(ps, 2);
        pd += __shfl_xor(pd, 1); pd += __shfl_xor(pd, 2);
        if (row < Nrows) {
            ushort4 pk;
            pk.x = f2bf(acc[r][0]);
            pk.y = f2bf(acc[r][1]);
            pk.z = f2bf(acc[r][2]);
            pk.w = f2bf(acc[r][3]);
            *(ushort4*)(Ybf + (size_t)row * 128 + cq * 4) = pk;
            if ((lane & 3) == 0) {
                a_srcO[row * 8 + h] = ps;
                a_dstO[row * 8 + h] = pd;
            }
        }
    }
}

// ---------- CSR build: histogram of dst + within-bucket rank (atomic return value) ----------
__global__ void hist_kernel(const int* __restrict__ ei, int E, int Etot,
                            int* __restrict__ counts, int* __restrict__ rank) {
    int eid = blockIdx.x * 256 + threadIdx.x;
    if (eid >= Etot) return;
    int s, d;
    edge_sd(ei, E, eid, s, d);
    rank[eid] = atomicAdd(&counts[d], 1);
}

// ---------- CSR build: parallel 3-stage exclusive scan ----------
__global__ __launch_bounds__(256) void chunksum_kernel(const int* __restrict__ counts,
                                                       int* __restrict__ csum, int N) {
    __shared__ int red[256];
    int base = blockIdx.x * 1024;
    int s = 0;
    for (int i = threadIdx.x; i < 1024; i += 256) {
        int idx = base + i;
        s += (idx < N) ? counts[idx] : 0;
    }
    red[threadIdx.x] = s;
    __syncthreads();
#pragma unroll
    for (int st = 128; st > 0; st >>= 1) {
        if (threadIdx.x < st) red[threadIdx.x] += red[threadIdx.x + st];
        __syncthreads();
    }
    if (threadIdx.x == 0) csum[blockIdx.x] = red[0];
}

__global__ void chunkscan_kernel(int* __restrict__ csum, int nchunk) {
    int lane = threadIdx.x;
    int v = (lane < nchunk) ? csum[lane] : 0;
    int incl = v;
#pragma unroll
    for (int off = 1; off < 64; off <<= 1) {
        int t = __shfl_up(incl, off);
        if (lane >= off) incl += t;
    }
    if (lane < nchunk) csum[lane] = incl - v;
}

__global__ __launch_bounds__(1024) void scanfinal_kernel(const int* __restrict__ counts,
                                                         const int* __restrict__ csum,
                                                         int* __restrict__ rowptr, int N) {
    __shared__ int wsum[16], woff_s[16];
    int tid = threadIdx.x, lane = tid & 63, wid = tid >> 6;
    int idx = blockIdx.x * 1024 + tid;
    int v = (idx < N) ? counts[idx] : 0;
    int incl = v;
#pragma unroll
    for (int off = 1; off < 64; off <<= 1) {
        int t = __shfl_up(incl, off);
        if (lane >= off) incl += t;
    }
    if (lane == 63) wsum[wid] = incl;
    __syncthreads();
    if (wid == 0 && lane < 16) {
        int w = wsum[lane], iw = w;
#pragma unroll
        for (int off = 1; off < 16; off <<= 1) {
            int t = __shfl_up(iw, off);
            if (lane >= off) iw += t;
        }
        woff_s[lane] = iw - w;
    }
    __syncthreads();
    if (idx < N) rowptr[idx + 1] = csum[blockIdx.x] + woff_s[wid] + incl;
    if (blockIdx.x == 0 && tid == 0) rowptr[0] = 0;
}

// ---------- CSR build: scatter src ids (NO atomics; rank precomputed in hist) ----------
__global__ void scatter_kernel(const int* __restrict__ ei, int E, int Etot,
                               const int* __restrict__ rowptr, const int* __restrict__ rank,
                               unsigned short* __restrict__ ssrc) {
    int eid = blockIdx.x * 256 + threadIdx.x;
    if (eid >= Etot) return;
    int s, d;
    edge_sd(ei, E, eid, s, d);
    ssrc[rowptr[d] + rank[eid]] = (unsigned short)s;
}

// ---------- fused softmax + aggregation: one wave per dst, 8 edges per iteration ----------
// Software-pipelined: row-gathers issued before exp/bpermute; next batch's ssrc/a_src
// prefetched during the FMA phase (breaks the serial load->exp->shuffle->load chain).
// MEAN=false: writes full [dst,128]. MEAN=true: head-mean fused -> writes [dst,16].
template <bool MEAN>
__global__ __launch_bounds__(256) void agg_kernel(const int* __restrict__ rowptr,
                                                  const unsigned short* __restrict__ ssrc,
                                                  const float* __restrict__ a_src,
                                                  const float* __restrict__ a_dst,
                                                  const unsigned short* __restrict__ Hbf,
                                                  float* __restrict__ outbuf, int N) {
    int wid = threadIdx.x >> 6;
    int dst = blockIdx.x * 4 + wid;
    if (dst >= N) return;
    int lane = threadIdx.x & 63;
    int j  = lane >> 3;      // edge slot 0..7 (exp phase)
    int hj = lane & 7;       // head (exp phase)
    int hf = lane >> 3;      // head owning this lane's feature pair (f/16)
    int f  = lane * 2;       // features f, f+1
    int start = rowptr[dst], end = rowptr[dst + 1];
    float adst = a_dst[dst * 8 + hj];

    float acc0 = 0.f, acc1 = 0.f, denl = 0.f;

    // prologue: first batch's src id + raw logit in flight
    int i = start + j;
    int s = (i < end) ? (int)ssrc[i] : -1;
    float ar = (s >= 0) ? a_src[s * 8 + hj] : 0.f;

    for (int base = start; base < end; base += 8) {
        // shuffle src ids FIRST and launch the 8 coalesced row-gathers immediately
        int sA[8];
#pragma unroll
        for (int j2 = 0; j2 < 8; j2++) sA[j2] = __shfl(s, j2 * 8);   // uniform lane -> readlane
        unsigned uA[8];
#pragma unroll
        for (int j2 = 0; j2 < 8; j2++)
            uA[j2] = (sA[j2] >= 0) ? *(const unsigned*)(Hbf + (size_t)sA[j2] * 128 + f) : 0u;

        // prefetch NEXT batch (overlaps with the gathers above + FMA below)
        int inext = base + 8 + j;
        int snext = (inext < end) ? (int)ssrc[inext] : -1;
        float anext = (snext >= 0) ? a_src[snext * 8 + hj] : 0.f;

        // exp + weight shuffle while row-gathers are in flight
        float w = (s >= 0) ? __expf(lrelu(ar + adst)) : 0.f;
        denl += w;
        float wA[8];
#pragma unroll
        for (int j2 = 0; j2 < 8; j2++) wA[j2] = __shfl(w, j2 * 8 + hf);   // bpermute

#pragma unroll
        for (int j2 = 0; j2 < 8; j2++) {
            acc0 += wA[j2] * __uint_as_float(uA[j2] << 16);
            acc1 += wA[j2] * __uint_as_float(uA[j2] & 0xffff0000u);
        }
        s = snext;
        ar = anext;
    }
    // reduce den over the 8 slots (stride-8 lanes share a head)
#pragma unroll
    for (int off = 8; off < 64; off <<= 1) denl += __shfl_xor(denl, off);
    float den = __shfl(denl, hf);
    float inv = 1.f / (den + 1e-16f);
    if (!MEAN) {
        *(float2*)(outbuf + (size_t)dst * 128 + f) = make_float2(acc0 * inv, acc1 * inv);
    } else {
        // head-mean: reduce features c=f&15 across the 8 heads (lanes sharing lane%8)
        float r0 = acc0 * inv, r1 = acc1 * inv;
#pragma unroll
        for (int off = 8; off < 64; off <<= 1) {
            r0 += __shfl_xor(r0, off);
            r1 += __shfl_xor(r1, off);
        }
        if (lane < 8)
            *(float2*)(outbuf + (size_t)dst * 16 + lane * 2) =
                make_float2(r0 * 0.125f, r1 * 0.125f);
    }
}

// ---------- batch-norm stats: two-stage deterministic reduction (NO atomics) ----------
template <int C>
__global__ __launch_bounds__(256) void stats_part_kernel(const float* __restrict__ X, int Nrows,
                                                         float* __restrict__ partial,
                                                         int rows_per_block) {
    constexpr int GSZ = 256 / C;
    __shared__ float ls[256], lq[256];
    int c = threadIdx.x % C;
    int g = threadIdx.x / C;
    long base = (long)blockIdx.x * rows_per_block;
    long endr = base + rows_per_block;
    if (endr > Nrows) endr = Nrows;
    float s = 0.f, q = 0.f;
    for (long r = base + g; r < endr; r += GSZ) {
        float v = X[r * C + c];
        s += v;
        q += v * v;
    }
    ls[threadIdx.x] = s;
    lq[threadIdx.x] = q;
    __syncthreads();
#pragma unroll
    for (int st = GSZ / 2; st > 0; st >>= 1) {
        if (g < st) {
            ls[threadIdx.x] += ls[threadIdx.x + st * C];
            lq[threadIdx.x] += lq[threadIdx.x + st * C];
        }
        __syncthreads();
    }
    if (g == 0) {
        partial[(size_t)blockIdx.x * (2 * C) + c] = ls[c];
        partial[(size_t)blockIdx.x * (2 * C) + C + c] = lq[c];
    }
}

// Stage 2: PARALLEL reduction of nblk partials (1024 threads, G groups per column).
template <int C>
__global__ __launch_bounds__(1024) void stats_final_kernel(const float* __restrict__ partial,
                                                           int nblk, float invN,
                                                           float* __restrict__ mu,
                                                           float* __restrict__ rsig) {
    constexpr int G = 1024 / C;
    __shared__ float ls[1024], lq[1024];
    int c = threadIdx.x % C;
    int g = threadIdx.x / C;
    float s = 0.f, q = 0.f;
    for (int b = g; b < nblk; b += G) {
        s += partial[(size_t)b * (2 * C) + c];
        q += partial[(size_t)b * (2 * C) + C + c];
    }
    ls[threadIdx.x] = s;
    lq[threadIdx.x] = q;
    __syncthreads();
#pragma unroll
    for (int st = G / 2; st > 0; st >>= 1) {
        if (g < st) {
            ls[threadIdx.x] += ls[threadIdx.x + st * C];
            lq[threadIdx.x] += lq[threadIdx.x + st * C];
        }
        __syncthreads();
    }
    if (g == 0) {
        float m_ = ls[c] * invN;
        float v = lq[c] * invN - m_ * m_;
        mu[c] = m_;
        rsig[c] = rsqrtf(v + BN_EPS);
    }
}

// ---------- final: BN(16) + logits = v @ Wc + bc ----------
__global__ void final_kernel(const float* __restrict__ out1,
                             const float* __restrict__ mu, const float* __restrict__ rsig,
                             const float* __restrict__ gamma, const float* __restrict__ beta,
                             const float* __restrict__ Wc, const float* __restrict__ bc,
                             float* __restrict__ out, int N) {
    int n = blockIdx.x * 256 + threadIdx.x;
    if (n >= N) return;
    float l0 = bc[0], l1 = bc[1];
#pragma unroll
    for (int c = 0; c < 16; c++) {
        float v = (out1[(size_t)n * 16 + c] - mu[c]) * rsig[c] * gamma[c] + beta[c];
        l0 += v * Wc[c * 2 + 0];
        l1 += v * Wc[c * 2 + 1];
    }
    out[(size_t)n * 2 + 0] = l0;
    out[(size_t)n * 2 + 1] = l1;
}

// ---------- launcher ----------
extern "C" void kernel_launch(void* const* d_in, const int* in_sizes, int n_in,
                              void* d_out, int out_size, void* d_ws, size_t ws_size,
                              hipStream_t stream) {
    const float* x   = (const float*)d_in[0];
    const int*   ei  = (const int*)d_in[1];
    const float* W0  = (const float*)d_in[2];
    const float* as0 = (const float*)d_in[3];
    const float* ad0 = (const float*)d_in[4];
    // d_in[5] = b0: cancelled exactly by the following batch-norm's mean subtraction
    const float* g0  = (const float*)d_in[6];
    const float* be0 = (const float*)d_in[7];
    const float* W1  = (const float*)d_in[8];
    const float* as1 = (const float*)d_in[9];
    const float* ad1 = (const float*)d_in[10];
    // d_in[11] = b1: cancelled by BN as well
    const float* g1  = (const float*)d_in[12];
    const float* be1 = (const float*)d_in[13];
    const float* Wc  = (const float*)d_in[14];
    const float* bc  = (const float*)d_in[15];
    float* out = (float*)d_out;

    int N = in_sizes[0] / 128;
    int E = in_sizes[1] / 2;
    int Etot = E + N;

    // workspace layout
    char* ws = (char*)d_ws;
    size_t off = 0;
    auto walloc = [&](size_t bytes) -> void* {
        void* p = ws + off;
        off += (bytes + 255) & ~(size_t)255;
        return p;
    };
    float*          B       = (float*)walloc((size_t)N * 128 * 4);
    unsigned short* Hbf     = (unsigned short*)walloc((size_t)N * 128 * 2);
    float*          a_src   = (float*)walloc((size_t)N * 8 * 4);
    float*          a_dst   = (float*)walloc((size_t)N * 8 * 4);
    float*          out1    = (float*)walloc((size_t)N * 16 * 4);
    int*            counts  = (int*)walloc((size_t)N * 4);
    int*            rowptr  = (int*)walloc((size_t)(N + 1) * 4);
    int*            rank    = (int*)walloc((size_t)Etot * 4);
    int*            csum    = (int*)walloc(64 * 4);
    unsigned short* ssrc    = (unsigned short*)walloc((size_t)Etot * 2);
    float*          partial = (float*)walloc((size_t)256 * 256 * 4);   // [256 blocks][2*128]
    float*          stats   = (float*)walloc(2 * 128 * 4);
    float* mu = stats, * rsig = stats + 128;

    dim3 b256(256);
    int gN64    = (N + 63) / 64;
    int gE      = (Etot + 255) / 256;
    int gAgg    = (N + 3) / 4;
    int nchunk  = (N + 1023) / 1024;
    const int SBLK = 256;
    int rpb = (N + SBLK - 1) / SBLK;

    // ---- CSR build (once; same graph for both layers) ----
    hipMemsetAsync(counts, 0, (size_t)N * 4, stream);
    hist_kernel<<<gE, b256, 0, stream>>>(ei, E, Etot, counts, rank);
    chunksum_kernel<<<nchunk, b256, 0, stream>>>(counts, csum, N);
    chunkscan_kernel<<<1, 64, 0, stream>>>(csum, nchunk);
    scanfinal_kernel<<<nchunk, 1024, 0, stream>>>(counts, csum, rowptr, N);
    scatter_kernel<<<gE, b256, 0, stream>>>(ei, E, Etot, rowptr, rank, ssrc);

    // ---- layer 0 (att logits fused into gemm epilogue; no fp32 h0 materialized) ----
    gemm128<<<gN64, b256, 0, stream>>>(x, W0, Hbf, as0, ad0, a_src, a_dst,
                                       nullptr, nullptr, nullptr, nullptr, N);
    agg_kernel<false><<<gAgg, b256, 0, stream>>>(rowptr, ssrc, a_src, a_dst, Hbf, B, N); // B = agg0
    stats_part_kernel<128><<<SBLK, b256, 0, stream>>>(B, N, partial, rpb);
    stats_final_kernel<128><<<1, 1024, 0, stream>>>(partial, SBLK, 1.0f / N, mu, rsig);

    // ---- layer 1 (BN+ELU fused into gemm X-load; att fused into epilogue) ----
    gemm128<<<gN64, b256, 0, stream>>>(B, W1, Hbf, as1, ad1, a_src, a_dst,
                                       mu, rsig, g0, be0, N);
    agg_kernel<true><<<gAgg, b256, 0, stream>>>(rowptr, ssrc, a_src, a_dst, Hbf, out1, N); // out1 = head-mean(agg1)
    stats_part_kernel<16><<<SBLK, b256, 0, stream>>>(out1, N, partial, rpb);
    stats_final_kernel<16><<<1, 1024, 0, stream>>>(partial, SBLK, 1.0f / N, mu, rsig);
    final_kernel<<<(N + 255) / 256, b256, 0, stream>>>(out1, mu, rsig, g1, be1, Wc, bc, out, N);
}